// Round 8
// baseline (171.321 us; speedup 1.0000x reference)
//
#include <hip/hip_runtime.h>
#include <hip/hip_bf16.h>

// MultiLinear: y[b,g,o] = sum_i x[b,g,i] * W[g,o,i] + bias[g,o]
// B=4096, G=16, DIN=512, DOUT=512, fp32 in/out.
// R8 = R4 skeleton (256x256, BK=64, 8 waves, double-buffered LDS, raw
// lgkm-only barriers) with the staging de-exposed:
//  (1) prepass converts W to bf16 in d_ws; B-side staged via global_load_lds
//      DMA (no VALU/regs/ds_writes), counted vmcnt(8) drains only the DMA.
//  (2) B LDS is linear [256][64]; bank conflicts fixed by XOR-swizzling the
//      *global* source per lane (T21: linear dest + inv-swz source + swz read).
//  (3) A-side fp32 reg-staging at prefetch distance 2 (raE/raO named sets,
//      static indexing), so the cvt+ds_write never waits on memory.

#define BATCH 4096
#define NGRP  16
#define DIN   512
#define DOUT  512

#define BM 256
#define BN 256
#define BK 64
#define NT (DIN / BK)   // 8 K-tiles
#define LDKA 72         // A pad: 144 B row stride (2-way bank alias = free)

typedef __bf16 bf16x8 __attribute__((ext_vector_type(8)));
typedef float  f32x4  __attribute__((ext_vector_type(4)));
typedef const __attribute__((address_space(1))) void gas_void;
typedef __attribute__((address_space(3))) void las_void;

// ---------- prepass: W fp32 -> bf16 into d_ws ----------
__global__ __launch_bounds__(256)
void wcvt_kernel(const float* __restrict__ W, __bf16* __restrict__ Wb) {
    const int i = (blockIdx.x * 256 + threadIdx.x) * 8;
    f32x4 a = *(const f32x4*)(W + i);
    f32x4 b = *(const f32x4*)(W + i + 4);
    bf16x8 v;
#pragma unroll
    for (int j = 0; j < 4; ++j) { v[j] = (__bf16)a[j]; v[j + 4] = (__bf16)b[j]; }
    *(bf16x8*)(Wb + i) = v;
}

// ---------- main GEMM ----------
__global__ __launch_bounds__(512, 2)
void MultiLinear_48498770706571_kernel(const float* __restrict__ X,
                                       const __bf16* __restrict__ Wb,
                                       const float* __restrict__ Bias,
                                       float* __restrict__ Y) {
    // 512 blocks / 8 XCDs = 64 consecutive tiles (2 full groups) per XCD.
    const int bid = (blockIdx.x & 7) * 64 + (blockIdx.x >> 3);
    const int g   = bid >> 5;          // 32 tiles per group (16 m x 2 n)
    const int mt  = (bid >> 1) & 15;
    const int nt  = bid & 1;
    const int bm0 = mt * BM;
    const int bn0 = nt * BN;

    __shared__ __bf16 As[2][BM][LDKA];   // 72 KB, reg-staged + cvt
    __shared__ __bf16 BsF[2][BN * BK];   // 64 KB, linear, DMA-filled

    const int tid  = threadIdx.x;
    const int lane = tid & 63;
    const int w    = tid >> 6;        // 0..7
    const int wm   = (w >> 2) * 128;  // {0,128}
    const int wn   = (w & 3) * 64;    // {0,64,128,192}
    const int l15  = lane & 15;
    const int kq   = (lane >> 4) * 8; // 0,8,16,24

    // A staging: 128 rows/pass (4 thr/row, 16 floats each), 2 passes.
    const int srow = tid >> 2;        // 0..127
    const int scol = (tid & 3) * 16;  // 0,16,32,48
    const float* pA = X + (size_t)(bm0 + srow) * (NGRP * DIN) + g * DIN + scol;
    const size_t strideA = (size_t)128 * (NGRP * DIN);

    // B DMA geometry: per wave 32 rows; 4 issues of 1 KB (8 rows each).
    const int drow0 = (w << 5) + (lane >> 3);   // + q*8
    const int dch   = lane & 7;                 // 16B chunk within row
    const __bf16* wbase = Wb + (size_t)g * (DOUT * DIN) + (size_t)bn0 * DIN;

    f32x4 raE[2][4], raO[2][4];

#define ISSUE_A(R, k0)                                                     \
    do {                                                                   \
        const f32x4* qa0 = (const f32x4*)(pA + (k0));                      \
        const f32x4* qa1 = (const f32x4*)(pA + strideA + (k0));            \
        R[0][0] = qa0[0]; R[0][1] = qa0[1]; R[0][2] = qa0[2]; R[0][3] = qa0[3]; \
        R[1][0] = qa1[0]; R[1][1] = qa1[1]; R[1][2] = qa1[2]; R[1][3] = qa1[3]; \
    } while (0)

#define CVT_WRITE_A(R, buf)                                                \
    do {                                                                   \
        _Pragma("unroll")                                                  \
        for (int p = 0; p < 2; ++p) {                                      \
            bf16x8 v0, v1;                                                 \
            _Pragma("unroll")                                              \
            for (int j = 0; j < 4; ++j) {                                  \
                v0[j] = (__bf16)R[p][0][j]; v0[j + 4] = (__bf16)R[p][1][j]; \
                v1[j] = (__bf16)R[p][2][j]; v1[j + 4] = (__bf16)R[p][3][j]; \
            }                                                              \
            *(bf16x8*)&As[buf][p * 128 + srow][scol]     = v0;             \
            *(bf16x8*)&As[buf][p * 128 + srow][scol + 8] = v1;             \
        }                                                                  \
    } while (0)

    // B: LDS linear; global source pre-swizzled so swizzled reads see right data.
#define DMA_B(kt, buf)                                                     \
    do {                                                                   \
        const size_t k0 = (size_t)(kt) * BK;                               \
        _Pragma("unroll")                                                  \
        for (int q = 0; q < 4; ++q) {                                      \
            const int row = drow0 + (q << 3);                              \
            const __bf16* gp = wbase + (size_t)row * DIN + k0              \
                               + ((dch ^ (row & 7)) << 3);                 \
            __builtin_amdgcn_global_load_lds(                              \
                (gas_void*)gp,                                             \
                (las_void*)&BsF[buf][(w << 11) + (q << 9)], 16, 0, 0);     \
        }                                                                  \
    } while (0)

#define COMPUTE(buf)                                                       \
    do {                                                                   \
        _Pragma("unroll")                                                  \
        for (int kk = 0; kk < 2; ++kk) {                                   \
            const int ko = kk * 32 + kq;                                   \
            bf16x8 af[8], bfr[4];                                          \
            _Pragma("unroll")                                              \
            for (int mi = 0; mi < 8; ++mi)                                 \
                af[mi] = *(const bf16x8*)&As[buf][wm + mi * 16 + l15][ko]; \
            _Pragma("unroll")                                              \
            for (int ni = 0; ni < 4; ++ni) {                               \
                const int brow = wn + ni * 16 + l15;                       \
                const int ch = (lane >> 4) + kk * 4;                       \
                bfr[ni] = *(const bf16x8*)&BsF[buf][brow * 64              \
                            + ((ch ^ (brow & 7)) << 3)];                   \
            }                                                              \
            _Pragma("unroll")                                              \
            for (int mi = 0; mi < 8; ++mi)                                 \
                _Pragma("unroll")                                          \
                for (int ni = 0; ni < 4; ++ni)                             \
                    acc[mi][ni] = __builtin_amdgcn_mfma_f32_16x16x32_bf16( \
                        af[mi], bfr[ni], acc[mi][ni], 0, 0, 0);            \
        }                                                                  \
    } while (0)

    f32x4 acc[8][4];
#pragma unroll
    for (int mi = 0; mi < 8; ++mi)
#pragma unroll
        for (int ni = 0; ni < 4; ++ni) acc[mi][ni] = f32x4{0.f, 0.f, 0.f, 0.f};

    // prologue: tile0 into buf0; A(tile1) in flight
    ISSUE_A(raE, 0);
    DMA_B(0, 0);
    CVT_WRITE_A(raE, 0);          // compiler waits raE (vmcnt 4: DMA may linger)
    ISSUE_A(raO, BK);

    for (int kt2 = 0; kt2 < NT; kt2 += 2) {
        // ===== even tile kt2 (buf 0) =====
        // outstanding: DMA(kt2)[4] older, raO[8] newer -> vmcnt(8) drains DMA only
        asm volatile("s_waitcnt vmcnt(8)" ::: "memory");
        asm volatile("s_waitcnt lgkmcnt(0)" ::: "memory");
        __builtin_amdgcn_s_barrier();
        DMA_B(kt2 + 1, 1);                          // kt2+1 <= 7 always
        if (kt2 + 2 < NT) ISSUE_A(raE, (kt2 + 2) * BK);
        COMPUTE(0);
        CVT_WRITE_A(raO, 1);                        // tile kt2+1 (always valid)

        // ===== odd tile kt2+1 (buf 1) =====
        if (kt2 + 3 < NT)
            asm volatile("s_waitcnt vmcnt(8)" ::: "memory");  // drains DMA(kt2+1)
        else
            asm volatile("s_waitcnt vmcnt(0)" ::: "memory");  // tail: only DMA left
        asm volatile("s_waitcnt lgkmcnt(0)" ::: "memory");
        __builtin_amdgcn_s_barrier();
        if (kt2 + 2 < NT) DMA_B(kt2 + 2, 0);
        if (kt2 + 3 < NT) ISSUE_A(raO, (kt2 + 3) * BK);
        COMPUTE(1);
        if (kt2 + 2 < NT) CVT_WRITE_A(raE, 0);      // tile kt2+2
    }

    // epilogue: C/D layout col = lane&15, row = (lane>>4)*4 + j (verified R1)
    const int r0 = (lane >> 4) * 4;
    const int c  = lane & 15;
    float bias_n[4];
#pragma unroll
    for (int ni = 0; ni < 4; ++ni)
        bias_n[ni] = Bias[g * DOUT + bn0 + wn + ni * 16 + c];
#pragma unroll
    for (int mi = 0; mi < 8; ++mi) {
#pragma unroll
        for (int j = 0; j < 4; ++j) {
            const int row = bm0 + wm + mi * 16 + r0 + j;
            float* yrow = Y + (size_t)row * (NGRP * DOUT) + g * DOUT + bn0 + wn;
#pragma unroll
            for (int ni = 0; ni < 4; ++ni)
                yrow[ni * 16 + c] = acc[mi][ni][j] + bias_n[ni];
        }
    }
#undef ISSUE_A
#undef CVT_WRITE_A
#undef DMA_B
#undef COMPUTE
}

extern "C" void kernel_launch(void* const* d_in, const int* in_sizes, int n_in,
                              void* d_out, int out_size, void* d_ws, size_t ws_size,
                              hipStream_t stream) {
    const float* X    = (const float*)d_in[0];
    const float* W    = (const float*)d_in[1];
    const float* Bias = (const float*)d_in[2];
    float* Y          = (float*)d_out;
    __bf16* Wb        = (__bf16*)d_ws;   // 8 MB scratch

    // prepass: 16*512*512 = 4M elems / (256 thr * 8) = 2048 blocks
    wcvt_kernel<<<2048, 256, 0, stream>>>(W, Wb);

    const int grid = NGRP * (BATCH / BM) * (DOUT / BN);  // 512
    MultiLinear_48498770706571_kernel<<<grid, 512, 0, stream>>>(X, Wb, Bias, Y);
}

// Round 9
// 84.042 us; speedup vs baseline: 2.0385x; 2.0385x over previous
//
#include <hip/hip_runtime.h>
#include <hip/hip_bf16.h>

// MultiLinear: y[b,g,o] = sum_i x[b,g,i] * W[g,o,i] + bias[g,o]
// B=4096, G=16, DIN=512, DOUT=512, fp32 in/out.
// R9 = R4 skeleton (256x256, BK=64, 8 waves, dbuf LDS, one lgkm-only raw
// barrier per K-tile) + R8's verified B-path (W->bf16 prepass, B staged via
// global_load_lds DMA with T21 swizzle: linear LDS dest + inv-swizzled
// global source + swizzled ds_read), MINUS R8's distance-2 A prefetch that
// spilled (WRITE_SIZE 302 MB of scratch). A-side: R4's distance-1 reg
// staging (32 regs). Arch VGPR ~95 < 128 cap; acc in 128 AGPRs.

#define BATCH 4096
#define NGRP  16
#define DIN   512
#define DOUT  512

#define BM 256
#define BN 256
#define BK 64
#define NT (DIN / BK)   // 8 K-tiles
#define LDKA 72         // A pad: 144 B row stride (2-way bank alias = free)

typedef __bf16 bf16x8 __attribute__((ext_vector_type(8)));
typedef float  f32x4  __attribute__((ext_vector_type(4)));
typedef const __attribute__((address_space(1))) void gas_void;
typedef __attribute__((address_space(3))) void las_void;

// ---------- prepass: W fp32 -> bf16 into d_ws ----------
__global__ __launch_bounds__(256)
void wcvt_kernel(const float* __restrict__ W, __bf16* __restrict__ Wb) {
    const int i = (blockIdx.x * 256 + threadIdx.x) * 8;
    f32x4 a = *(const f32x4*)(W + i);
    f32x4 b = *(const f32x4*)(W + i + 4);
    bf16x8 v;
#pragma unroll
    for (int j = 0; j < 4; ++j) { v[j] = (__bf16)a[j]; v[j + 4] = (__bf16)b[j]; }
    *(bf16x8*)(Wb + i) = v;
}

// ---------- main GEMM ----------
__global__ __launch_bounds__(512, 2)
void MultiLinear_48498770706571_kernel(const float* __restrict__ X,
                                       const __bf16* __restrict__ Wb,
                                       const float* __restrict__ Bias,
                                       float* __restrict__ Y) {
    // 512 blocks / 8 XCDs = 64 consecutive tiles (2 full groups) per XCD.
    const int bid = (blockIdx.x & 7) * 64 + (blockIdx.x >> 3);
    const int g   = bid >> 5;          // 32 tiles per group (16 m x 2 n)
    const int mt  = (bid >> 1) & 15;
    const int nt  = bid & 1;
    const int bm0 = mt * BM;
    const int bn0 = nt * BN;

    __shared__ __bf16 As[2][BM][LDKA];   // 72 KB, reg-staged + cvt
    __shared__ __bf16 BsF[2][BN * BK];   // 64 KB, linear, DMA-filled

    const int tid  = threadIdx.x;
    const int lane = tid & 63;
    const int w    = tid >> 6;        // 0..7
    const int wm   = (w >> 2) * 128;  // {0,128}
    const int wn   = (w & 3) * 64;    // {0,64,128,192}
    const int l15  = lane & 15;
    const int kq   = (lane >> 4) * 8; // 0,8,16,24

    // A staging: 128 rows/pass (4 thr/row, 16 floats each), 2 passes.
    const int srow = tid >> 2;        // 0..127
    const int scol = (tid & 3) * 16;  // 0,16,32,48
    const float* pA = X + (size_t)(bm0 + srow) * (NGRP * DIN) + g * DIN + scol;
    const size_t strideA = (size_t)128 * (NGRP * DIN);

    // B DMA geometry: per wave 32 rows; 4 issues of 1 KB (8 rows x 128 B).
    const int drow0 = (w << 5) + (lane >> 3);   // + q*8
    const int dch   = lane & 7;                 // 16 B chunk within row
    const __bf16* wbase = Wb + (size_t)g * (DOUT * DIN) + (size_t)bn0 * DIN;

    f32x4 ra[2][4];   // 32 VGPRs in flight (A only; B is DMA)

#define ISSUE_A(k0)                                                        \
    do {                                                                   \
        const f32x4* qa0 = (const f32x4*)(pA + (k0));                      \
        const f32x4* qa1 = (const f32x4*)(pA + strideA + (k0));            \
        ra[0][0] = qa0[0]; ra[0][1] = qa0[1]; ra[0][2] = qa0[2]; ra[0][3] = qa0[3]; \
        ra[1][0] = qa1[0]; ra[1][1] = qa1[1]; ra[1][2] = qa1[2]; ra[1][3] = qa1[3]; \
    } while (0)

#define CVT_WRITE_A(buf)                                                   \
    do {                                                                   \
        _Pragma("unroll")                                                  \
        for (int p = 0; p < 2; ++p) {                                      \
            bf16x8 v0, v1;                                                 \
            _Pragma("unroll")                                              \
            for (int j = 0; j < 4; ++j) {                                  \
                v0[j] = (__bf16)ra[p][0][j]; v0[j + 4] = (__bf16)ra[p][1][j]; \
                v1[j] = (__bf16)ra[p][2][j]; v1[j + 4] = (__bf16)ra[p][3][j]; \
            }                                                              \
            *(bf16x8*)&As[buf][p * 128 + srow][scol]     = v0;             \
            *(bf16x8*)&As[buf][p * 128 + srow][scol + 8] = v1;             \
        }                                                                  \
    } while (0)

    // B: LDS linear dest; global source pre-swizzled; reads swizzle back.
#define DMA_B(kt, buf)                                                     \
    do {                                                                   \
        const size_t k0 = (size_t)(kt) * BK;                               \
        _Pragma("unroll")                                                  \
        for (int q = 0; q < 4; ++q) {                                      \
            const int row = drow0 + (q << 3);                              \
            const __bf16* gp = wbase + (size_t)row * DIN + k0              \
                               + ((dch ^ (row & 7)) << 3);                 \
            __builtin_amdgcn_global_load_lds(                              \
                (gas_void*)gp,                                             \
                (las_void*)&BsF[buf][(w << 11) + (q << 9)], 16, 0, 0);     \
        }                                                                  \
    } while (0)

#define COMPUTE(buf)                                                       \
    do {                                                                   \
        _Pragma("unroll")                                                  \
        for (int kk = 0; kk < 2; ++kk) {                                   \
            const int ko = kk * 32 + kq;                                   \
            bf16x8 af[8], bfr[4];                                          \
            _Pragma("unroll")                                              \
            for (int mi = 0; mi < 8; ++mi)                                 \
                af[mi] = *(const bf16x8*)&As[buf][wm + mi * 16 + l15][ko]; \
            _Pragma("unroll")                                              \
            for (int ni = 0; ni < 4; ++ni) {                               \
                const int brow = wn + ni * 16 + l15;                       \
                const int ch = (lane >> 4) + kk * 4;                       \
                bfr[ni] = *(const bf16x8*)&BsF[buf][brow * 64              \
                            + ((ch ^ (brow & 7)) << 3)];                   \
            }                                                              \
            _Pragma("unroll")                                              \
            for (int mi = 0; mi < 8; ++mi)                                 \
                _Pragma("unroll")                                          \
                for (int ni = 0; ni < 4; ++ni)                             \
                    acc[mi][ni] = __builtin_amdgcn_mfma_f32_16x16x32_bf16( \
                        af[mi], bfr[ni], acc[mi][ni], 0, 0, 0);            \
        }                                                                  \
    } while (0)

    f32x4 acc[8][4];
#pragma unroll
    for (int mi = 0; mi < 8; ++mi)
#pragma unroll
        for (int ni = 0; ni < 4; ++ni) acc[mi][ni] = f32x4{0.f, 0.f, 0.f, 0.f};

    // prologue: A(0) regs + DMA B(0) into buf0; write A(0); prefetch A(1).
    ISSUE_A(0);
    DMA_B(0, 0);
    CVT_WRITE_A(0);      // compiler drains A(0) (older than DMA? no: A first,
                         // so vmcnt(4) leaves DMA(0) in flight)
    ISSUE_A(BK);         // outstanding: DMA(0)[4] + A(1)[8]

    for (int kt = 0; kt < NT; ++kt) {
        const int cur = kt & 1;
        // Drain DMA(kt): outstanding = DMA(kt)[4 oldest] + A(kt+1)[8 newer].
        if (kt + 1 < NT)
            asm volatile("s_waitcnt vmcnt(8)" ::: "memory");
        else
            asm volatile("s_waitcnt vmcnt(0)" ::: "memory");  // tail: DMA only
        asm volatile("s_waitcnt lgkmcnt(0)" ::: "memory");
        __builtin_amdgcn_s_barrier();

        // after barrier: all waves done reading buf cur^1 -> WAR-safe to refill
        if (kt + 1 < NT) DMA_B(kt + 1, cur ^ 1);

        COMPUTE(cur);

        if (kt + 1 < NT) {
            CVT_WRITE_A(cur ^ 1);          // drains A(kt+1), leaves DMA in flight
            if (kt + 2 < NT) ISSUE_A((kt + 2) * BK);
        }
    }

    // epilogue: C/D layout col = lane&15, row = (lane>>4)*4 + j (verified R1)
    const int r0 = (lane >> 4) * 4;
    const int c  = lane & 15;
    float bias_n[4];
#pragma unroll
    for (int ni = 0; ni < 4; ++ni)
        bias_n[ni] = Bias[g * DOUT + bn0 + wn + ni * 16 + c];
#pragma unroll
    for (int mi = 0; mi < 8; ++mi) {
#pragma unroll
        for (int j = 0; j < 4; ++j) {
            const int row = bm0 + wm + mi * 16 + r0 + j;
            float* yrow = Y + (size_t)row * (NGRP * DOUT) + g * DOUT + bn0 + wn;
#pragma unroll
            for (int ni = 0; ni < 4; ++ni)
                yrow[ni * 16 + c] = acc[mi][ni][j] + bias_n[ni];
        }
    }
#undef ISSUE_A
#undef CVT_WRITE_A
#undef DMA_B
#undef COMPUTE
}

extern "C" void kernel_launch(void* const* d_in, const int* in_sizes, int n_in,
                              void* d_out, int out_size, void* d_ws, size_t ws_size,
                              hipStream_t stream) {
    const float* X    = (const float*)d_in[0];
    const float* W    = (const float*)d_in[1];
    const float* Bias = (const float*)d_in[2];
    float* Y          = (float*)d_out;
    __bf16* Wb        = (__bf16*)d_ws;   // 8 MB scratch

    // prepass: 16*512*512 = 4M elems / (256 thr * 8 elems) = 2048 blocks
    wcvt_kernel<<<2048, 256, 0, stream>>>(W, Wb);

    const int grid = NGRP * (BATCH / BM) * (DOUT / BN);  // 512
    MultiLinear_48498770706571_kernel<<<grid, 512, 0, stream>>>(X, Wb, Bias, Y);
}